// Round 1
// 1883.290 us; speedup vs baseline: 1.1065x; 1.1065x over previous
//
#include <hip/hip_runtime.h>
#include <stdint.h>

// Problem constants (from reference setup_inputs)
#define Bdim 4
#define Tdim 256
#define Hdim 2048
#define Vdim 64000
#define MROWS (Bdim * Tdim)        // 1024 token rows
#define NTILES (Vdim / 128)        // 500 vocab tiles of 128
#define NKSTEPS (Hdim / 32)        // 64 K-steps
#define BETA 0.1f
#define IGNORE_INDEX (-100)

typedef __bf16 bf16x8 __attribute__((ext_vector_type(8)));
typedef float floatx4 __attribute__((ext_vector_type(4)));

// ---------------------------------------------------------------------------
// fp32 -> bf16 (RTNE) cast, 8 elems/thread, fully coalesced
// ---------------------------------------------------------------------------
__device__ __forceinline__ unsigned int f2bf(float f) {
  unsigned int u = __float_as_uint(f);
  return (u + 0x7FFFu + ((u >> 16) & 1u)) >> 16;
}

__global__ void cast_kernel(const float* __restrict__ src,
                            unsigned short* __restrict__ dst, long long n) {
  long long i = ((long long)blockIdx.x * blockDim.x + threadIdx.x) * 8;
  if (i + 8 <= n) {
    float4 f0 = *(const float4*)(src + i);
    float4 f1 = *(const float4*)(src + i + 4);
    uint4 o;
    o.x = f2bf(f0.x) | (f2bf(f0.y) << 16);
    o.y = f2bf(f0.z) | (f2bf(f0.w) << 16);
    o.z = f2bf(f1.x) | (f2bf(f1.y) << 16);
    o.w = f2bf(f1.z) | (f2bf(f1.w) << 16);
    *(uint4*)(dst + i) = o;
  }
}

// ---------------------------------------------------------------------------
// async global -> LDS, 16B per lane (wave-uniform base + lane*16)
// ---------------------------------------------------------------------------
__device__ __forceinline__ void async_load16(const unsigned short* g,
                                             unsigned short* l) {
  __builtin_amdgcn_global_load_lds(
      (const __attribute__((address_space(1))) void*)g,
      (__attribute__((address_space(3))) void*)l, 16, 0, 0);
}

// ---------------------------------------------------------------------------
// Fused GEMM + partial logsumexp.
// A = x_bf16 [1024][2048], Wb = W_bf16 [64000][2048] (both K-major).
//
// Structural changes vs previous version:
//  * 1D grid of 4000 with XCD-aware swizzle: logical tile L = nb*8+mb,
//    L = (f&7)*500 + (f>>3). All 8 m-blocks of one n-tile are consecutive
//    same-XCD dispatch slots -> W tile fetched once into one L2.
//  * Double-buffered LDS staging with counted s_waitcnt vmcnt(4): next
//    K-tile's global_load_lds stay in flight across the barrier (no
//    vmcnt(0) drain inside the main loop).
//  * LDS bank-conflict swizzle (both-sides, involution slot ^= (row>>1)&3):
//    LDS destination stays linear (global_load_lds constraint); global
//    SOURCE address is pre-swizzled; ds_read applies the same XOR.
// ---------------------------------------------------------------------------
__global__ void __launch_bounds__(256)
gemm_lse_kernel(const unsigned short* __restrict__ A,
                const unsigned short* __restrict__ Wb,
                const int* __restrict__ y,
                float* __restrict__ partials,
                float* __restrict__ tgt) {
  __shared__ unsigned short sA[2][128 * 32];  // 2 x 8 KB
  __shared__ unsigned short sB[2][128 * 32];  // 2 x 8 KB
  __shared__ float sRM[2][128];               // cross-wave (wn) merge
  __shared__ float sRS[2][128];

  const int tid = threadIdx.x;
  const int lane = tid & 63;
  const int wave = tid >> 6;
  const int wm = wave >> 1;   // wave row (0..1)
  const int wn = wave & 1;    // wave col (0..1)
  const int lr = lane & 15;   // row-in-16 for A frag / col for C
  const int kq = lane >> 4;   // k-quad (0..3)

  // XCD-aware swizzle (nwg = 4000, divisible by 8 -> bijective simple form)
  const int f = blockIdx.x;
  const int L = (f & 7) * 500 + (f >> 3);
  const int nb = L >> 3;            // vocab tile 0..499
  const int mb = L & 7;             // token tile 0..7
  const int m0 = mb * 128;
  const int n0 = nb * 128;

  // ---- staging source pointers (pre-swizzled slot, rule #21) ----
  // Physical chunk c (0..511): row = c>>2, phys slot = c&3. The data stored
  // there is logical slot sl = sp ^ ((row>>1)&3).
  const int c0 = tid;
  const int c1 = tid + 256;
  const int r0 = c0 >> 2, r1 = c1 >> 2;
  const int s0 = (c0 & 3) ^ ((r0 >> 1) & 3);
  const int s1 = (c1 & 3) ^ ((r1 >> 1) & 3);
  const unsigned short* gA0 = A + (size_t)(m0 + r0) * Hdim + s0 * 8;
  const unsigned short* gA1 = A + (size_t)(m0 + r1) * Hdim + s1 * 8;
  const unsigned short* gB0 = Wb + (size_t)(n0 + r0) * Hdim + s0 * 8;
  const unsigned short* gB1 = Wb + (size_t)(n0 + r1) * Hdim + s1 * 8;
  unsigned short* lA0base = &sA[0][c0 * 8];
  unsigned short* lA1base = &sA[0][c1 * 8];
  unsigned short* lB0base = &sB[0][c0 * 8];
  unsigned short* lB1base = &sB[0][c1 * 8];

  // ---- fragment read offsets (same XOR involution on the read side) ----
  // row fields don't carry into each other: r = wm*64 + i*16 + lr, so
  // (r>>1)&3 == (lr>>1)&3, constant per lane.
  const int slotE = (kq ^ ((lr >> 1) & 3)) * 8;
  const int offA = (wm * 64 + lr) * 32 + slotE;
  const int offB = (wn * 64 + lr) * 32 + slotE;

  floatx4 acc[4][4];
#pragma unroll
  for (int i = 0; i < 4; ++i)
#pragma unroll
    for (int j = 0; j < 4; ++j) acc[i][j] = (floatx4){0.f, 0.f, 0.f, 0.f};

  auto stage = [&](int buf, int koff) {
    const int lo = buf * (128 * 32);
    async_load16(gA0 + koff, lA0base + lo);
    async_load16(gA1 + koff, lA1base + lo);
    async_load16(gB0 + koff, lB0base + lo);
    async_load16(gB1 + koff, lB1base + lo);
  };

  // prologue: fill buffer 0
  stage(0, 0);

  for (int kt = 0; kt < NKSTEPS; ++kt) {
    const int cur = kt & 1;
    if (kt + 1 < NKSTEPS) {
      stage(cur ^ 1, (kt + 1) * 32);
      // wait only for the 4 older loads (current buffer); next tile's 4
      // stay in flight across the barrier (T4 counted vmcnt).
      asm volatile("s_waitcnt vmcnt(4)" ::: "memory");
    } else {
      asm volatile("s_waitcnt vmcnt(0)" ::: "memory");
    }
    __builtin_amdgcn_s_barrier();
    asm volatile("" ::: "memory");  // pin LDS reads below the barrier

    const unsigned short* bufA = &sA[cur][0];
    const unsigned short* bufB = &sB[cur][0];
    bf16x8 af[4], bv[4];
#pragma unroll
    for (int i = 0; i < 4; ++i)
      af[i] = *(const bf16x8*)&bufA[offA + i * 512];
#pragma unroll
    for (int j = 0; j < 4; ++j)
      bv[j] = *(const bf16x8*)&bufB[offB + j * 512];

#pragma unroll
    for (int i = 0; i < 4; ++i)
#pragma unroll
      for (int j = 0; j < 4; ++j)
        acc[i][j] = __builtin_amdgcn_mfma_f32_16x16x32_bf16(af[i], bv[j],
                                                            acc[i][j], 0, 0, 0);

    // all ds_reads complete before any wave can pass this barrier and
    // overwrite buf[cur] at the next iteration's stage()
    asm volatile("s_waitcnt lgkmcnt(0)" ::: "memory");
    __builtin_amdgcn_s_barrier();
    asm volatile("" ::: "memory");
  }

  // Epilogue: per-row (max, sumexp) over this wave's 64 cols, then merge wn.
  // C/D layout: col = wn*64 + j*16 + lr ; row = wm*64 + i*16 + kq*4 + reg.
#pragma unroll
  for (int mi = 0; mi < 4; ++mi) {
#pragma unroll
    for (int rg = 0; rg < 4; ++rg) {
      float v0 = acc[mi][0][rg], v1 = acc[mi][1][rg];
      float v2 = acc[mi][2][rg], v3 = acc[mi][3][rg];
      float mx = fmaxf(fmaxf(v0, v1), fmaxf(v2, v3));
#pragma unroll
      for (int d = 1; d < 16; d <<= 1) mx = fmaxf(mx, __shfl_xor(mx, d));
      float sm = expf(v0 - mx) + expf(v1 - mx) + expf(v2 - mx) + expf(v3 - mx);
#pragma unroll
      for (int d = 1; d < 16; d <<= 1) sm += __shfl_xor(sm, d);

      int row_l = wm * 64 + mi * 16 + kq * 4 + rg;
      if (lr == 0) {
        sRM[wn][row_l] = mx;
        sRS[wn][row_l] = sm;
      }

      // target-logit scatter (exactly one lane in the whole grid matches)
      int row_g = m0 + row_l;
      int tcol = y[row_g];
      int lc = tcol - (n0 + wn * 64);
      if (lc >= 0 && lc < 64 && (lc & 15) == lr) {
        int ni = lc >> 4;
        float tv = (ni == 0) ? acc[mi][0][rg]
                 : (ni == 1) ? acc[mi][1][rg]
                 : (ni == 2) ? acc[mi][2][rg]
                             : acc[mi][3][rg];
        tgt[row_g] = tv;
      }
    }
  }
  __syncthreads();

  if (tid < 128) {
    float ma = sRM[0][tid], mb2 = sRM[1][tid];
    float M = fmaxf(ma, mb2);
    float S = sRS[0][tid] * expf(ma - M) + sRS[1][tid] * expf(mb2 - M);
    *(float2*)&partials[((size_t)(m0 + tid) * NTILES + nb) * 2] =
        make_float2(M, S);
  }
}

// ---------------------------------------------------------------------------
// Combine partials across 500 vocab tiles -> per-token logp. One wave / row.
// ---------------------------------------------------------------------------
__global__ void combine_kernel(const float* __restrict__ partials,
                               const float* __restrict__ tgt,
                               const int* __restrict__ y,
                               float* __restrict__ tlogp) {
  int lane = threadIdx.x & 63;
  int row = blockIdx.x * (blockDim.x >> 6) + (threadIdx.x >> 6);
  float m = -__builtin_inff();
  float s = 0.f;
  for (int t = lane; t < NTILES; t += 64) {
    float2 p = *(const float2*)&partials[((size_t)row * NTILES + t) * 2];
    float nm = fmaxf(m, p.x);
    s = s * expf(m - nm) + p.y * expf(p.x - nm);
    m = nm;
  }
#pragma unroll
  for (int d = 1; d < 64; d <<= 1) {
    float om = __shfl_xor(m, d);
    float os = __shfl_xor(s, d);
    float nm = fmaxf(m, om);
    s = s * expf(m - nm) + os * expf(om - nm);
    m = nm;
  }
  if (lane == 0) {
    int yv = y[row];
    float lse = m + logf(s);
    tlogp[row] = (yv != IGNORE_INDEX) ? (tgt[row] - lse) : 0.f;
  }
}

// ---------------------------------------------------------------------------
// Final: sequence means -> DPO loss + rewards (5 floats)
// ---------------------------------------------------------------------------
__global__ void final_kernel(const float* __restrict__ tlogp,
                             const int* __restrict__ y,
                             float* __restrict__ out) {
  __shared__ float redv[4], redk[4];
  __shared__ float seq[2][4];
  int tid = threadIdx.x, lane = tid & 63, w = tid >> 6;
  for (int m = 0; m < 2; ++m) {
    for (int b = 0; b < 4; ++b) {
      int row = b * Tdim + tid;  // Tdim == blockDim == 256
      float v = tlogp[m * MROWS + row];
      float k = (y[row] != IGNORE_INDEX) ? 1.f : 0.f;
#pragma unroll
      for (int d = 1; d < 64; d <<= 1) {
        v += __shfl_xor(v, d);
        k += __shfl_xor(k, d);
      }
      if (lane == 0) { redv[w] = v; redk[w] = k; }
      __syncthreads();
      if (tid == 0)
        seq[m][b] = (redv[0] + redv[1] + redv[2] + redv[3]) /
                    (redk[0] + redk[1] + redk[2] + redk[3]);
      __syncthreads();
    }
  }
  if (tid == 0) {
    float cl0 = seq[0][0] - seq[1][0];
    float cl1 = seq[0][1] - seq[1][1];
    float rl0 = seq[0][2] - seq[1][2];
    float rl1 = seq[0][3] - seq[1][3];
    float d0 = BETA * (cl0 - rl0);
    float d1 = BETA * (cl1 - rl1);
    // -log_sigmoid(d) = softplus(-d), numerically stable
    float l0 = d0 > 0.f ? log1pf(expf(-d0)) : (-d0 + log1pf(expf(d0)));
    float l1 = d1 > 0.f ? log1pf(expf(-d1)) : (-d1 + log1pf(expf(d1)));
    out[0] = 0.5f * (l0 + l1);
    out[1] = BETA * cl0;
    out[2] = BETA * cl1;
    out[3] = BETA * rl0;
    out[4] = BETA * rl1;
  }
}

// ---------------------------------------------------------------------------
extern "C" void kernel_launch(void* const* d_in, const int* in_sizes, int n_in,
                              void* d_out, int out_size, void* d_ws,
                              size_t ws_size, hipStream_t stream) {
  const float* x     = (const float*)d_in[0];
  const float* ref_x = (const float*)d_in[1];
  const int*   y     = (const int*)d_in[2];
  const float* W     = (const float*)d_in[3];
  const float* ref_W = (const float*)d_in[4];
  float* out = (float*)d_out;

  // Workspace layout (models processed sequentially; big buffers reused):
  //   Wb   : 64000*2048 bf16 = 262,144,000 B
  //   xb   :  1024*2048 bf16 =   4,194,304 B
  //   part : 1024*500*2 f32  =   4,096,000 B
  //   tgt  : 1024 f32        =       4,096 B
  //   tlogp: 2*1024 f32      =       8,192 B   (kept across both models)
  char* ws = (char*)d_ws;
  unsigned short* Wb = (unsigned short*)ws;
  unsigned short* xb = (unsigned short*)(ws + 262144000LL);
  float* partials    = (float*)(ws + 262144000LL + 4194304LL);
  float* tgt         = (float*)(ws + 262144000LL + 4194304LL + 4096000LL);
  float* tlogp       = (float*)(ws + 262144000LL + 4194304LL + 4096000LL + 4096LL);

  const long long nW = (long long)Vdim * Hdim;   // 131,072,000
  const long long nX = (long long)MROWS * Hdim;  //   2,097,152

  for (int model = 0; model < 2; ++model) {
    const float* xm = model ? ref_x : x;
    const float* Wm = model ? ref_W : W;
    cast_kernel<<<(unsigned)(nW / (8 * 256)), 256, 0, stream>>>(Wm, Wb, nW);
    cast_kernel<<<(unsigned)(nX / (8 * 256)), 256, 0, stream>>>(xm, xb, nX);
    gemm_lse_kernel<<<MROWS / 128 * NTILES, 256, 0, stream>>>(
        xb, Wb, y, partials, tgt);
    combine_kernel<<<MROWS / 4, 256, 0, stream>>>(partials, tgt, y,
                                                  tlogp + model * MROWS);
  }
  final_kernel<<<1, 256, 0, stream>>>(tlogp, y, out);
}